// Round 5
// baseline (5190.107 us; speedup 1.0000x reference)
//
#include <hip/hip_runtime.h>

#define NB 32
#define NT 512
#define NI 128
#define NH 1024
#define NG 4096
#define NO 128

typedef _Float16 f16;
typedef _Float16 f16x8 __attribute__((ext_vector_type(8)));
typedef float f32x4 __attribute__((ext_vector_type(4)));
typedef unsigned long long ull;

#define MFMA16(a, b, c) __builtin_amdgcn_mfma_f32_16x16x32_f16(a, b, c, 0, 0, 0)

__device__ __forceinline__ float sigm(float x) { return 1.f / (1.f + __expf(-x)); }
__device__ __forceinline__ float tanh_(float x) {
    float a = fabsf(x);
    float e = __expf(-2.f * a);
    float r = (1.f - e) / (1.f + e);
    return x < 0.f ? -r : r;
}
// true when NO halfword of x equals the 0x7F7F sentinel (f16 NaN pattern;
// |h|<1 so real h never encodes as it)
__device__ __forceinline__ bool nosent(ull x) {
    ull y = x ^ 0x7F7F7F7F7F7F7F7FULL;
    return !(((y - 0x0001000100010001ULL) & ~y) & 0x8000800080008000ULL);
}
__device__ __forceinline__ void astore64(void* p, ull v) {
    __hip_atomic_store((ull*)p, v, __ATOMIC_RELAXED, __HIP_MEMORY_SCOPE_AGENT);
}
__device__ __forceinline__ f16x8 ld8f(const float* s) {
    float4 x0 = *(const float4*)s, x1 = *(const float4*)(s + 4);
    f16x8 v;
    v[0] = (f16)x0.x; v[1] = (f16)x0.y; v[2] = (f16)x0.z; v[3] = (f16)x0.w;
    v[4] = (f16)x1.x; v[5] = (f16)x1.y; v[6] = (f16)x1.z; v[7] = (f16)x1.w;
    return v;
}

__global__ void convf16(const float* __restrict__ src, f16* __restrict__ dst, int n) {
    int i = blockIdx.x * blockDim.x + threadIdx.x;
    if (i < n) dst[i] = (f16)src[i];
}

// ---------------------------------------------------------------------------
// Persistent pipeline: 256 WGs x 256 thr, 1 WG/CU (forced by 84KB dyn LDS).
//  bid [0,128)   R1: layer-1 step, (16 batch, 16 units)/CU, K=1152 (state|h1).
//  bid [128,256) R2: layer-2 step + input proj, (16 batch, 16 units)/CU,
//                two K=1024 matmuls (h1[t]@Wih1 + h2[t-1]@Whh1).
// Weights in VGPRs (K split across 4 waves, 4 gates). A-fragments go straight
// from global loads into MFMA. Producers publish packed 8B agent-scope
// atomic stores (write-through to L3). Consumers bulk-read with PLAIN
// dwordx4 loads; if any fragment still holds the 0x7F7F sentinel, they issue
// an agent acquire fence (buffer_inv: invalidates stale L1/L2 lines) and
// re-issue plain loads for the pending fragments — keeping all traffic
// cacheline-granular and L2-shared within an XCD. No flags, no rings ->
// deadlock-impossible. LDS holds only the padded K-reduction buffer.
// ---------------------------------------------------------------------------
extern "C" __global__ __launch_bounds__(256, 1) void persist(
    const float* __restrict__ Wih0f, const float* __restrict__ Whh0f, const float* __restrict__ b0,
    const float* __restrict__ Wih1f, const float* __restrict__ Whh1f, const float* __restrict__ b1,
    const f16* __restrict__ state16,
    f16* __restrict__ h1all,      // [NT][NB][NH], 0x7F-filled
    f16* __restrict__ h2all)      // [NT][NB][NH], 0x7F-filled
{
    extern __shared__ char smem[];
    float* gbuf = (float*)smem;   // [16][16*17] f32 partials, +17 pad
    const int bid = blockIdx.x;
    const int tid = threadIdx.x;
    const int w = tid >> 6;
    const int lane = tid & 63;
    const int llo = lane & 15;
    const int lhi = lane >> 4;
    const int rb = tid >> 2;        // elementwise: batch row (threads 0..63)
    const int uq = (tid & 3) * 4;   // elementwise: unit quad base

    if (bid < 128) {
        // ============================ R1 ============================
        const int bs = bid >> 6, us = bid & 63;
        const int bbase = bs * 16, ubase = us * 16;
        // weights: wave w owns ks = w*9+i (K=1152), 4 gate-column blocks
        f16x8 wr[36];
#pragma unroll
        for (int g = 0; g < 4; ++g)
#pragma unroll
            for (int i = 0; i < 9; ++i) {
                int kpos = (w * 9 + i) * 32 + lhi * 8;
                int col = g * NH + ubase + llo;
                const float* s = (kpos < 128) ? (Wih0f + (size_t)col * NI + kpos)
                                              : (Whh0f + (size_t)col * NH + (kpos - 128));
                wr[g * 9 + i] = ld8f(s);
            }
        float cc[4] = {0.f, 0.f, 0.f, 0.f};
        float Bi[4], Bff[4], Bg[4], Bo[4];
        if (tid < 64) {
#pragma unroll
            for (int u = 0; u < 4; ++u) {
                Bi[u]  = b0[0 * NH + ubase + uq + u];
                Bff[u] = b0[1 * NH + ubase + uq + u];
                Bg[u]  = b0[2 * NH + ubase + uq + u];
                Bo[u]  = b0[3 * NH + ubase + uq + u];
            }
        }

        for (int t = 0; t < NT; ++t) {
            const f16* hprev = h1all + (size_t)(t - 1) * NB * NH;
            const int row = bbase + llo;
            // ---- bulk plain loads, sentinel-validate, fence+plain retry ----
            f16x8 val[9];
#pragma unroll
            for (int i = 0; i < 9; ++i) {
                int kpos = (w * 9 + i) * 32 + lhi * 8;
                if (kpos < 128)
                    val[i] = *(const f16x8*)(state16 + ((size_t)row * NT + t) * NI + kpos);
                else if (t > 0)
                    val[i] = *(const f16x8*)(hprev + (size_t)row * NH + (kpos - 128));
                else
                    val[i] = f16x8{};
            }
            if (t > 0) {
                unsigned pend = 0;
#pragma unroll
                for (int i = 0; i < 9; ++i) {
                    int kpos = (w * 9 + i) * 32 + lhi * 8;
                    if (kpos >= 128) {
                        ull a = ((ull*)&val[i])[0], b = ((ull*)&val[i])[1];
                        if (!(nosent(a) && nosent(b))) pend |= 1u << i;
                    }
                }
                while (__builtin_expect(pend != 0, 0)) {
                    // invalidate stale L1/L2 lines, then re-stream pending frags
                    __builtin_amdgcn_fence(__ATOMIC_ACQUIRE, "agent");
#pragma unroll
                    for (int i = 0; i < 9; ++i)
                        if (pend & (1u << i)) {
                            int kpos = (w * 9 + i) * 32 + lhi * 8;
                            val[i] = *(const f16x8*)(hprev + (size_t)row * NH + (kpos - 128));
                        }
#pragma unroll
                    for (int i = 0; i < 9; ++i)
                        if (pend & (1u << i)) {
                            ull a = ((ull*)&val[i])[0], b = ((ull*)&val[i])[1];
                            if (nosent(a) && nosent(b)) pend &= ~(1u << i);
                        }
                    if (pend) __builtin_amdgcn_s_sleep(1);
                }
            }
            // ---- MFMA directly on loaded fragments (K-split partials) ----
            f32x4 acc[4] = {};
#pragma unroll
            for (int i = 0; i < 9; ++i)
#pragma unroll
                for (int g = 0; g < 4; ++g)
                    acc[g] = MFMA16(val[i], wr[g * 9 + i], acc[g]);
            __syncthreads();   // gbuf free (prev step's reads done)
#pragma unroll
            for (int g = 0; g < 4; ++g)
#pragma unroll
                for (int r = 0; r < 4; ++r)
                    gbuf[(w * 4 + g) * 272 + (lhi * 4 + r) * 17 + llo] = acc[g][r];
            __syncthreads();
            // ---- reduce + elementwise + packed publish (threads 0..63) ----
            if (tid < 64) {
                ull pack = 0;
#pragma unroll
                for (int u = 0; u < 4; ++u) {
                    int un = uq + u;
                    float s0 = 0, s1 = 0, s2 = 0, s3 = 0;
#pragma unroll
                    for (int w2 = 0; w2 < 4; ++w2) {
                        s0 += gbuf[(w2 * 4 + 0) * 272 + rb * 17 + un];
                        s1 += gbuf[(w2 * 4 + 1) * 272 + rb * 17 + un];
                        s2 += gbuf[(w2 * 4 + 2) * 272 + rb * 17 + un];
                        s3 += gbuf[(w2 * 4 + 3) * 272 + rb * 17 + un];
                    }
                    float i_ = sigm(s0 + Bi[u]), f_ = sigm(s1 + Bff[u]);
                    float g_ = tanh_(s2 + Bg[u]), o_ = sigm(s3 + Bo[u]);
                    cc[u] = f_ * cc[u] + i_ * g_;
                    float h = o_ * tanh_(cc[u]);
                    unsigned short hb = __builtin_bit_cast(unsigned short, (f16)h);
                    pack |= (ull)hb << (16 * u);
                }
                astore64(h1all + ((size_t)t * NB + bbase + rb) * NH + ubase + uq, pack);
            }
        }
    } else {
        // ====================== R2 (merged P) ======================
        const int b2 = bid - 128, bs = b2 >> 6, us = b2 & 63;
        const int bbase = bs * 16, ubase = us * 16;
        f16x8 wr1[32], wr2[32];   // Wih1, Whh1: wave w owns ks = w*8+i
#pragma unroll
        for (int g = 0; g < 4; ++g)
#pragma unroll
            for (int i = 0; i < 8; ++i) {
                int kpos = (w * 8 + i) * 32 + lhi * 8;
                int col = g * NH + ubase + llo;
                wr1[g * 8 + i] = ld8f(Wih1f + (size_t)col * NH + kpos);
                wr2[g * 8 + i] = ld8f(Whh1f + (size_t)col * NH + kpos);
            }
        float cc[4] = {0.f, 0.f, 0.f, 0.f};
        float Bi[4], Bff[4], Bg[4], Bo[4];
        if (tid < 64) {
#pragma unroll
            for (int u = 0; u < 4; ++u) {
                Bi[u]  = b1[0 * NH + ubase + uq + u];
                Bff[u] = b1[1 * NH + ubase + uq + u];
                Bg[u]  = b1[2 * NH + ubase + uq + u];
                Bo[u]  = b1[3 * NH + ubase + uq + u];
            }
        }
        const int row = bbase + llo;

        auto check8 = [&](f16x8* v) -> unsigned {
            unsigned p = 0;
#pragma unroll
            for (int i = 0; i < 8; ++i) {
                ull a = ((ull*)&v[i])[0], b = ((ull*)&v[i])[1];
                if (!(nosent(a) && nosent(b))) p |= 1u << i;
            }
            return p;
        };

        for (int t = 0; t < NT; ++t) {
            const f16* A1 = h1all + (size_t)t * NB * NH;
            const f16* A2 = h2all + (size_t)(t - 1) * NB * NH;
            f16x8 v1[8], v2[8];
#pragma unroll
            for (int i = 0; i < 8; ++i) {
                int kpos = (w * 8 + i) * 32 + lhi * 8;
                v1[i] = *(const f16x8*)(A1 + (size_t)row * NH + kpos);
            }
            if (t > 0) {
#pragma unroll
                for (int i = 0; i < 8; ++i) {
                    int kpos = (w * 8 + i) * 32 + lhi * 8;
                    v2[i] = *(const f16x8*)(A2 + (size_t)row * NH + kpos);
                }
            } else {
#pragma unroll
                for (int i = 0; i < 8; ++i) v2[i] = f16x8{};
            }
            unsigned p1 = check8(v1);
            unsigned p2 = (t > 0) ? check8(v2) : 0u;
            while (__builtin_expect((p1 | p2) != 0, 0)) {
                __builtin_amdgcn_fence(__ATOMIC_ACQUIRE, "agent");
#pragma unroll
                for (int i = 0; i < 8; ++i) {
                    int kpos = (w * 8 + i) * 32 + lhi * 8;
                    if (p1 & (1u << i)) v1[i] = *(const f16x8*)(A1 + (size_t)row * NH + kpos);
                    if (p2 & (1u << i)) v2[i] = *(const f16x8*)(A2 + (size_t)row * NH + kpos);
                }
#pragma unroll
                for (int i = 0; i < 8; ++i) {
                    if (p1 & (1u << i)) {
                        ull a = ((ull*)&v1[i])[0], b = ((ull*)&v1[i])[1];
                        if (nosent(a) && nosent(b)) p1 &= ~(1u << i);
                    }
                    if (p2 & (1u << i)) {
                        ull a = ((ull*)&v2[i])[0], b = ((ull*)&v2[i])[1];
                        if (nosent(a) && nosent(b)) p2 &= ~(1u << i);
                    }
                }
                if (p1 | p2) __builtin_amdgcn_s_sleep(1);
            }

            f32x4 acc[4] = {};
#pragma unroll
            for (int i = 0; i < 8; ++i)
#pragma unroll
                for (int g = 0; g < 4; ++g) {
                    acc[g] = MFMA16(v1[i], wr1[g * 8 + i], acc[g]);
                    acc[g] = MFMA16(v2[i], wr2[g * 8 + i], acc[g]);
                }
            __syncthreads();
#pragma unroll
            for (int g = 0; g < 4; ++g)
#pragma unroll
                for (int r = 0; r < 4; ++r)
                    gbuf[(w * 4 + g) * 272 + (lhi * 4 + r) * 17 + llo] = acc[g][r];
            __syncthreads();
            if (tid < 64) {
                ull pack = 0;
#pragma unroll
                for (int u = 0; u < 4; ++u) {
                    int un = uq + u;
                    float s0 = 0, s1 = 0, s2 = 0, s3 = 0;
#pragma unroll
                    for (int w2 = 0; w2 < 4; ++w2) {
                        s0 += gbuf[(w2 * 4 + 0) * 272 + rb * 17 + un];
                        s1 += gbuf[(w2 * 4 + 1) * 272 + rb * 17 + un];
                        s2 += gbuf[(w2 * 4 + 2) * 272 + rb * 17 + un];
                        s3 += gbuf[(w2 * 4 + 3) * 272 + rb * 17 + un];
                    }
                    float i_ = sigm(s0 + Bi[u]), f_ = sigm(s1 + Bff[u]);
                    float g_ = tanh_(s2 + Bg[u]), o_ = sigm(s3 + Bo[u]);
                    cc[u] = f_ * cc[u] + i_ * g_;
                    float h = o_ * tanh_(cc[u]);
                    unsigned short hb = __builtin_bit_cast(unsigned short, (f16)h);
                    pack |= (ull)hb << (16 * u);
                }
                astore64(h2all + ((size_t)t * NB + bbase + rb) * NH + ubase + uq, pack);
            }
        }
    }
}

// ---------------------------------------------------------------------------
// Head: out[b][t][o] = h2[b][t][:] @ W_out^T + b_out ; one WG per t
// ---------------------------------------------------------------------------
__device__ __forceinline__ void stage_h(const f16* __restrict__ hsrc, char* smem, int tid) {
    const float4* src = (const float4*)hsrc;
#pragma unroll
    for (int i = 0; i < 16; ++i) {
        int c = i * 256 + tid;
        int off = c * 16;
        int swz = off ^ (((off >> 11) & 7) << 4);
        *(float4*)(smem + swz) = src[c];
    }
}
__device__ __forceinline__ f16x8 afrag(const char* smem, int row, int kk) {
    int off = (row << 11) + kk * 2;
    off ^= ((row & 7) << 4);
    return *(const f16x8*)(smem + off);
}

__global__ __launch_bounds__(256) void head_kernel(
    const f16* __restrict__ h2all, const f16* __restrict__ Wout,
    const float* __restrict__ bout, float* __restrict__ out)
{
    __shared__ __align__(16) char smem[65536];
    int t = blockIdx.x;
    int tid = threadIdx.x;
    int wave = tid >> 6, lane = tid & 63, lhi = lane >> 4, llo = lane & 15;
    stage_h(h2all + (size_t)t * NB * NH, smem, tid);
    __syncthreads();

    f32x4 acc[2][2];
#pragma unroll
    for (int nt = 0; nt < 2; ++nt) {
        int col = wave * 32 + nt * 16 + llo;
        float bb = bout[col];
#pragma unroll
        for (int r = 0; r < 4; ++r) { acc[0][nt][r] = bb; acc[1][nt][r] = bb; }
    }
#pragma unroll 8
    for (int kt = 0; kt < 32; ++kt) {
        int kk = kt * 32 + lhi * 8;
        f16x8 a0 = afrag(smem, llo, kk);
        f16x8 a1 = afrag(smem, 16 + llo, kk);
#pragma unroll
        for (int nt = 0; nt < 2; ++nt) {
            int col = wave * 32 + nt * 16 + llo;
            f16x8 bf = *(const f16x8*)(Wout + (size_t)col * NH + kk);
            acc[0][nt] = MFMA16(a0, bf, acc[0][nt]);
            acc[1][nt] = MFMA16(a1, bf, acc[1][nt]);
        }
    }
#pragma unroll
    for (int nt = 0; nt < 2; ++nt) {
        int col = wave * 32 + nt * 16 + llo;
#pragma unroll
        for (int r = 0; r < 4; ++r) {
            out[(size_t)(lhi * 4 + r) * NT * NO + (size_t)t * NO + col] = acc[0][nt][r];
            out[(size_t)(16 + lhi * 4 + r) * NT * NO + (size_t)t * NO + col] = acc[1][nt][r];
        }
    }
}

extern "C" void kernel_launch(void* const* d_in, const int* in_sizes, int n_in,
                              void* d_out, int out_size, void* d_ws, size_t ws_size,
                              hipStream_t stream)
{
    const float* state = (const float*)d_in[0];
    const float* Wih0f = (const float*)d_in[1];
    const float* Whh0f = (const float*)d_in[2];
    const float* b0    = (const float*)d_in[3];
    const float* Wih1f = (const float*)d_in[4];
    const float* Whh1f = (const float*)d_in[5];
    const float* b1    = (const float*)d_in[6];
    const float* Woutf = (const float*)d_in[7];
    const float* bout  = (const float*)d_in[8];
    float* out = (float*)d_out;
    (void)in_sizes; (void)n_in; (void)out_size; (void)ws_size;

    size_t off = 0;
    char* base = (char*)d_ws;
    auto alloc = [&](size_t bytes) -> void* {
        void* p = base + off;
        off += (bytes + 255) & ~(size_t)255;
        return p;
    };
    f16* state16 = (f16*)alloc((size_t)NB * NT * NI * 2);
    f16* Wout    = (f16*)alloc((size_t)NO * NH * 2);
    f16* h1all   = (f16*)alloc((size_t)NT * NB * NH * 2);
    f16* h2all   = (f16*)alloc((size_t)NT * NB * NH * 2);

    convf16<<<(NB * NT * NI + 255) / 256, 256, 0, stream>>>(state, state16, NB * NT * NI);
    convf16<<<(NO * NH + 255) / 256, 256, 0, stream>>>(Woutf, Wout, NO * NH);
    // sentinel-fill h1all+h2all (contiguous) — also erases harness poison
    hipMemsetAsync(h1all, 0x7F, (size_t)2 * NT * NB * NH * 2, stream);

    hipFuncSetAttribute((const void*)persist,
                        hipFuncAttributeMaxDynamicSharedMemorySize, 86016);
    persist<<<256, 256, 86016, stream>>>(Wih0f, Whh0f, b0, Wih1f, Whh1f, b1,
                                         state16, h1all, h2all);
    head_kernel<<<NT, 256, 0, stream>>>(h2all, Wout, bout, out);
}